// Round 2
// baseline (295.045 us; speedup 1.0000x reference)
//
#include <hip/hip_runtime.h>
#include <stdint.h>

typedef __attribute__((ext_vector_type(8))) short bf16x8;
typedef __attribute__((ext_vector_type(4))) float f32x4;

__device__ __forceinline__ unsigned short f2bf(float f) {
  unsigned int u = __builtin_bit_cast(unsigned int, f);
  u += 0x7fffu + ((u >> 16) & 1u);
  return (unsigned short)(u >> 16);
}

__device__ __forceinline__ void gload16(const void* g, void* l) {
  __builtin_amdgcn_global_load_lds(
      (const __attribute__((address_space(1))) void*)g,
      (__attribute__((address_space(3))) void*)l, 16, 0, 0);
}

// ---------------- f32 -> bf16 conversion ----------------
__global__ void cvt_kernel(const float* __restrict__ in,
                           unsigned short* __restrict__ out, int n4) {
  int i = blockIdx.x * blockDim.x + threadIdx.x;
  if (i < n4) {
    float4 v = ((const float4*)in)[i];
    ushort4 o;
    o.x = f2bf(v.x); o.y = f2bf(v.y); o.z = f2bf(v.z); o.w = f2bf(v.w);
    ((ushort4*)out)[i] = o;
  }
}

// ---------------- GEMM: C = A * B^T  (A [M,K] bf16, B [N,K] bf16) ----------
// EPI: 0 = bf16 out, 1 = f32 out, 2 = +bias,relu -> bf16, 3 = +bias -> f32,
//      4 = bf16 out written transposed per-head (Vt layout [B*H*64, 1024])
template <int EPI>
__global__ __launch_bounds__(256, 2) void gemm_bt(
    const unsigned short* __restrict__ A, const unsigned short* __restrict__ B,
    void* __restrict__ C, const float* __restrict__ bias, int M, int N, int K) {
  __shared__ unsigned short Al[128 * 32];
  __shared__ unsigned short Bl[128 * 32];
  const int tid = threadIdx.x;
  const int lane = tid & 63;
  const int wid = tid >> 6;
  const int wr = wid >> 1;
  const int wc = wid & 1;
  const int m0 = blockIdx.y * 128;
  const int n0 = blockIdx.x * 128;

  f32x4 acc[4][4];
#pragma unroll
  for (int i = 0; i < 4; ++i)
#pragma unroll
    for (int j = 0; j < 4; ++j) acc[i][j] = f32x4{0.f, 0.f, 0.f, 0.f};

  const int srow = wid * 32 + (lane >> 2);
  const int scol = (lane & 3) * 8;
  const unsigned short* Ag = A + (size_t)(m0 + srow) * K + scol;
  const unsigned short* Bg = B + (size_t)(n0 + srow) * K + scol;
  unsigned short* Ald = &Al[wid * 32 * 32];
  unsigned short* Bld = &Bl[wid * 32 * 32];
  const size_t K16 = (size_t)16 * K;

  const int ko = (lane >> 4) * 8;
  const int arow = wr * 64 + (lane & 15);
  const int brow = wc * 64 + (lane & 15);

  for (int kt = 0; kt < K; kt += 32) {
    __syncthreads();
    gload16(Ag + kt, Ald);
    gload16(Ag + K16 + kt, Ald + 16 * 32);
    gload16(Bg + kt, Bld);
    gload16(Bg + K16 + kt, Bld + 16 * 32);
    __syncthreads();
    bf16x8 af[4], bf[4];
#pragma unroll
    for (int mi = 0; mi < 4; ++mi)
      af[mi] = *(const bf16x8*)&Al[(arow + mi * 16) * 32 + ko];
#pragma unroll
    for (int ni = 0; ni < 4; ++ni)
      bf[ni] = *(const bf16x8*)&Bl[(brow + ni * 16) * 32 + ko];
#pragma unroll
    for (int mi = 0; mi < 4; ++mi)
#pragma unroll
      for (int ni = 0; ni < 4; ++ni)
        acc[mi][ni] = __builtin_amdgcn_mfma_f32_16x16x32_bf16(
            af[mi], bf[ni], acc[mi][ni], 0, 0, 0);
  }

  const int rl = (lane >> 4) * 4;
  const int cl = lane & 15;
#pragma unroll
  for (int mi = 0; mi < 4; ++mi) {
#pragma unroll
    for (int ni = 0; ni < 4; ++ni) {
      const int r0 = m0 + wr * 64 + mi * 16 + rl;
      const int c = n0 + wc * 64 + ni * 16 + cl;
      if (EPI == 4) {
        // Vt[(b*8+h)*64 + dd][s] = C[r][c],  b=r>>10, s=r&1023, h=c>>6, dd=c&63
        ushort4 pk;
        pk.x = f2bf(acc[mi][ni][0]);
        pk.y = f2bf(acc[mi][ni][1]);
        pk.z = f2bf(acc[mi][ni][2]);
        pk.w = f2bf(acc[mi][ni][3]);
        const int b_ = r0 >> 10, s_ = r0 & 1023, h_ = c >> 6, dd = c & 63;
        *(ushort4*)((unsigned short*)C +
                    ((size_t)((b_ * 8 + h_) * 64 + dd) * 1024 + s_)) = pk;
      } else {
#pragma unroll
        for (int j = 0; j < 4; ++j) {
          float v = acc[mi][ni][j];
          if (EPI == 2 || EPI == 3) v += bias[c];
          if (EPI == 2) v = fmaxf(v, 0.f);
          if (EPI == 1 || EPI == 3)
            ((float*)C)[(size_t)(r0 + j) * N + c] = v;
          else
            ((unsigned short*)C)[(size_t)(r0 + j) * N + c] = f2bf(v);
        }
      }
    }
  }
}

// ---------------- flash attention with additive cost bias ----------------
// grid (16, 64): x = q-tile of 64 rows, y = b*8+h. 4 waves, 16 q-rows each.
__global__ __launch_bounds__(256, 2) void attn_kernel(
    const unsigned short* __restrict__ Q, const unsigned short* __restrict__ K,
    const unsigned short* __restrict__ V,  // Vt layout [B*H*64, 1024]
    const float* __restrict__ cost, unsigned short* __restrict__ ctx) {
  __shared__ unsigned short P[4][16 * 80];  // per-wave P tile, padded stride 80
  const int tid = threadIdx.x, lane = tid & 63, wid = tid >> 6;
  const int bh = blockIdx.y, b = bh >> 3, h = bh & 7;
  const int q0 = blockIdx.x * 64 + wid * 16;
  const int cl = lane & 15, gl = lane >> 4;

  const unsigned short* qp =
      Q + (size_t)(b * 1024 + q0 + cl) * 512 + h * 64 + gl * 8;
  const bf16x8 qf0 = *(const bf16x8*)qp;
  const bf16x8 qf1 = *(const bf16x8*)(qp + 32);

  f32x4 acc[4];
  float m_run[4], l_run[4];
#pragma unroll
  for (int i = 0; i < 4; ++i) {
    acc[i] = f32x4{0.f, 0.f, 0.f, 0.f};
    m_run[i] = -1e30f;
    l_run[i] = 0.f;
  }

  const float* costp = cost + (size_t)(b * 1024 + q0 + gl * 4) * 1024;

  for (int k0 = 0; k0 < 1024; k0 += 64) {
    f32x4 s[4];
#pragma unroll
    for (int ni = 0; ni < 4; ++ni) {
      const unsigned short* kp =
          K + (size_t)(b * 1024 + k0 + ni * 16 + cl) * 512 + h * 64 + gl * 8;
      f32x4 t = f32x4{0.f, 0.f, 0.f, 0.f};
      t = __builtin_amdgcn_mfma_f32_16x16x32_bf16(qf0, *(const bf16x8*)kp, t,
                                                  0, 0, 0);
      t = __builtin_amdgcn_mfma_f32_16x16x32_bf16(
          qf1, *(const bf16x8*)(kp + 32), t, 0, 0, 0);
#pragma unroll
      for (int j = 0; j < 4; ++j)
        s[ni][j] = t[j] * 0.125f + costp[(size_t)j * 1024 + k0 + ni * 16 + cl];
    }
    float alpha[4], rs[4];
#pragma unroll
    for (int j = 0; j < 4; ++j) {
      float m = fmaxf(fmaxf(s[0][j], s[1][j]), fmaxf(s[2][j], s[3][j]));
      m = fmaxf(m, __shfl_xor(m, 1));
      m = fmaxf(m, __shfl_xor(m, 2));
      m = fmaxf(m, __shfl_xor(m, 4));
      m = fmaxf(m, __shfl_xor(m, 8));
      const float mnew = fmaxf(m_run[j], m);
      alpha[j] = __expf(m_run[j] - mnew);
      m_run[j] = mnew;
      rs[j] = 0.f;
    }
#pragma unroll
    for (int ni = 0; ni < 4; ++ni)
#pragma unroll
      for (int j = 0; j < 4; ++j) {
        float p = __expf(s[ni][j] - m_run[j]);
        s[ni][j] = p;
        rs[j] += p;
      }
#pragma unroll
    for (int j = 0; j < 4; ++j) {
      float r = rs[j];
      r += __shfl_xor(r, 1);
      r += __shfl_xor(r, 2);
      r += __shfl_xor(r, 4);
      r += __shfl_xor(r, 8);
      l_run[j] = l_run[j] * alpha[j] + r;
    }
#pragma unroll
    for (int nv = 0; nv < 4; ++nv)
#pragma unroll
      for (int j = 0; j < 4; ++j) acc[nv][j] *= alpha[j];
    // P (C-layout) -> LDS -> A-fragment layout
#pragma unroll
    for (int ni = 0; ni < 4; ++ni)
#pragma unroll
      for (int j = 0; j < 4; ++j)
        P[wid][(gl * 4 + j) * 80 + ni * 16 + cl] = f2bf(s[ni][j]);
    bf16x8 pf0 = *(const bf16x8*)&P[wid][cl * 80 + gl * 8];
    bf16x8 pf1 = *(const bf16x8*)&P[wid][cl * 80 + 32 + gl * 8];
#pragma unroll
    for (int nv = 0; nv < 4; ++nv) {
      const unsigned short* vp =
          V + (size_t)(bh * 64 + nv * 16 + cl) * 1024 + k0 + gl * 8;
      acc[nv] = __builtin_amdgcn_mfma_f32_16x16x32_bf16(
          pf0, *(const bf16x8*)vp, acc[nv], 0, 0, 0);
      acc[nv] = __builtin_amdgcn_mfma_f32_16x16x32_bf16(
          pf1, *(const bf16x8*)(vp + 32), acc[nv], 0, 0, 0);
    }
  }
#pragma unroll
  for (int nv = 0; nv < 4; ++nv)
#pragma unroll
    for (int j = 0; j < 4; ++j) {
      float v = acc[nv][j] / l_run[j];
      ctx[(size_t)(b * 1024 + q0 + gl * 4 + j) * 512 + h * 64 + nv * 16 + cl] =
          f2bf(v);
    }
}

// ---------------- fused residual + LayerNorm (rows of 512) ----------------
__global__ __launch_bounds__(256) void ln_kernel(
    const float* __restrict__ x1, const float* __restrict__ x2,
    const float* __restrict__ g, const float* __restrict__ bt,
    float* __restrict__ o32, unsigned short* __restrict__ obf) {
  const int lane = threadIdx.x & 63, wid = threadIdx.x >> 6;
  const int row = blockIdx.x * 4 + wid;
  const float4* p1 = (const float4*)(x1 + (size_t)row * 512);
  const float4* p2 = (const float4*)(x2 + (size_t)row * 512);
  float4 a0 = p1[lane * 2], a1 = p1[lane * 2 + 1];
  float4 b0 = p2[lane * 2], b1 = p2[lane * 2 + 1];
  float x[8] = {a0.x + b0.x, a0.y + b0.y, a0.z + b0.z, a0.w + b0.w,
                a1.x + b1.x, a1.y + b1.y, a1.z + b1.z, a1.w + b1.w};
  float sum = 0.f, sq = 0.f;
#pragma unroll
  for (int i = 0; i < 8; ++i) {
    sum += x[i];
    sq += x[i] * x[i];
  }
#pragma unroll
  for (int m = 1; m <= 32; m <<= 1) {
    sum += __shfl_xor(sum, m);
    sq += __shfl_xor(sq, m);
  }
  const float mean = sum * (1.f / 512.f);
  const float var = sq * (1.f / 512.f) - mean * mean;
  const float rstd = rsqrtf(var + 1e-6f);
  float y[8];
#pragma unroll
  for (int i = 0; i < 8; ++i) {
    const int c = lane * 8 + i;
    y[i] = (x[i] - mean) * rstd * g[c] + bt[c];
  }
  float4* op = (float4*)(o32 + (size_t)row * 512);
  op[lane * 2] = make_float4(y[0], y[1], y[2], y[3]);
  op[lane * 2 + 1] = make_float4(y[4], y[5], y[6], y[7]);
  if (obf) {
    ushort4 u0, u1;
    u0.x = f2bf(y[0]); u0.y = f2bf(y[1]); u0.z = f2bf(y[2]); u0.w = f2bf(y[3]);
    u1.x = f2bf(y[4]); u1.y = f2bf(y[5]); u1.z = f2bf(y[6]); u1.w = f2bf(y[7]);
    ushort4* ob = (ushort4*)(obf + (size_t)row * 512);
    ob[lane * 2] = u0;
    ob[lane * 2 + 1] = u1;
  }
}

extern "C" void kernel_launch(void* const* d_in, const int* in_sizes, int n_in,
                              void* d_out, int out_size, void* d_ws,
                              size_t ws_size, hipStream_t stream) {
  const float* enc = (const float*)d_in[0];
  const float* cost = (const float*)d_in[1];
  const float* wq = (const float*)d_in[2];
  const float* wk = (const float*)d_in[3];
  const float* wv = (const float*)d_in[4];
  const float* fcw = (const float*)d_in[5];
  const float* ln1g = (const float*)d_in[6];
  const float* ln1b = (const float*)d_in[7];
  const float* w1 = (const float*)d_in[8];
  const float* b1 = (const float*)d_in[9];
  const float* w2 = (const float*)d_in[10];
  const float* b2 = (const float*)d_in[11];
  const float* ln2g = (const float*)d_in[12];
  const float* ln2b = (const float*)d_in[13];

  char* ws = (char*)d_ws;
  size_t off = 0;
  auto alloc = [&](size_t n) {
    void* p = ws + off;
    off += (n + 255) & ~(size_t)255;
    return p;
  };
  const size_t MD = 8192ull * 512;    // M x D elements
  const size_t MF = 8192ull * 2048;   // M x DF elements
  unsigned short* enc_bf = (unsigned short*)alloc(MD * 2);
  unsigned short* wq_bf = (unsigned short*)alloc(512 * 512 * 2);
  unsigned short* wk_bf = (unsigned short*)alloc(512 * 512 * 2);
  unsigned short* wv_bf = (unsigned short*)alloc(512 * 512 * 2);
  unsigned short* fcw_bf = (unsigned short*)alloc(512 * 512 * 2);
  unsigned short* w1_bf = (unsigned short*)alloc(2048 * 512 * 2);
  unsigned short* w2_bf = (unsigned short*)alloc(512 * 2048 * 2);
  unsigned short* Qb = (unsigned short*)alloc(MD * 2);
  unsigned short* Kb = (unsigned short*)alloc(MD * 2);
  unsigned short* Vt = (unsigned short*)alloc(MD * 2);
  unsigned short* ctx_bf = (unsigned short*)alloc(MD * 2);
  float* fc_out = (float*)alloc(MD * 4);  // reused as ffn output
  float* attn32 = (float*)alloc(MD * 4);
  unsigned short* attn_bf = (unsigned short*)alloc(MD * 2);
  unsigned short* h_bf = (unsigned short*)alloc(MF * 2);

  // f32 -> bf16 conversions
  cvt_kernel<<<4096, 256, 0, stream>>>(enc, enc_bf, (int)(MD / 4));
  cvt_kernel<<<256, 256, 0, stream>>>(wq, wq_bf, 65536);
  cvt_kernel<<<256, 256, 0, stream>>>(wk, wk_bf, 65536);
  cvt_kernel<<<256, 256, 0, stream>>>(wv, wv_bf, 65536);
  cvt_kernel<<<256, 256, 0, stream>>>(fcw, fcw_bf, 65536);
  cvt_kernel<<<1024, 256, 0, stream>>>(w1, w1_bf, 262144);
  cvt_kernel<<<1024, 256, 0, stream>>>(w2, w2_bf, 262144);

  // Q/K/V projections
  gemm_bt<0><<<dim3(4, 64), 256, 0, stream>>>(enc_bf, wq_bf, Qb, nullptr, 8192,
                                              512, 512);
  gemm_bt<0><<<dim3(4, 64), 256, 0, stream>>>(enc_bf, wk_bf, Kb, nullptr, 8192,
                                              512, 512);
  gemm_bt<4><<<dim3(4, 64), 256, 0, stream>>>(enc_bf, wv_bf, Vt, nullptr, 8192,
                                              512, 512);
  // attention
  attn_kernel<<<dim3(16, 64), 256, 0, stream>>>(Qb, Kb, Vt, cost, ctx_bf);
  // fc projection, then LN1 (+enc residual)
  gemm_bt<1><<<dim3(4, 64), 256, 0, stream>>>(ctx_bf, fcw_bf, fc_out, nullptr,
                                              8192, 512, 512);
  ln_kernel<<<2048, 256, 0, stream>>>(fc_out, enc, ln1g, ln1b, attn32, attn_bf);
  // FFN
  gemm_bt<2><<<dim3(16, 64), 256, 0, stream>>>(attn_bf, w1_bf, h_bf, b1, 8192,
                                               2048, 512);
  gemm_bt<3><<<dim3(4, 64), 256, 0, stream>>>(h_bf, w2_bf, fc_out, b2, 8192,
                                              512, 2048);
  // LN2 (+attn_out residual) -> final output
  ln_kernel<<<2048, 256, 0, stream>>>(fc_out, attn32, ln2g, ln2b, (float*)d_out,
                                      nullptr);
}